// Round 1
// baseline (1479.668 us; speedup 1.0000x reference)
//
#include <hip/hip_runtime.h>
#include <hip/hip_bf16.h>

#define VOCAB_SZ 267735
#define NROWS 512

typedef __attribute__((ext_vector_type(8))) short bf16x8;
typedef __attribute__((ext_vector_type(4))) float f32x4;

enum { MODE_Y = 0, MODE_REDUCE = 1, MODE_WRITE = 2 };

// Generic C[512, N] = A[512, K](bf16) @ B[N, K](fp32, converted while staging)^T
// Tile: BM=128, BN=128, BK=32; 256 threads = 4 waves in 2x2; each wave 64x64 via
// 4x4 frags of v_mfma_f32_16x16x32_bf16.
// A-frag: lane holds A[m=lane&15][k=(lane>>4)*8 + j]; B-frag symmetric (n=lane&15).
// C/D: col=lane&15, row=(lane>>4)*4+reg  (learn_hip m89/m91 verified).
template<int MODE>
__global__ __launch_bounds__(256)
void gemm_k(const __hip_bfloat16* __restrict__ A, int lda, int Kloop, int K,
            const float* __restrict__ B, const float* __restrict__ B2,
            int Nmat, int Nsplit,
            const float* __restrict__ bias, const float* __restrict__ bias2,
            float* __restrict__ rowsum,
            const float* __restrict__ adj,
            float* __restrict__ outp, int Nstore,
            __hip_bfloat16* __restrict__ yout, int yld, int ywidth)
{
    const int t = threadIdx.x;
    const int col0 = blockIdx.x * 128;
    const int row0 = blockIdx.y * 128;
    const int wid = t >> 6, lane = t & 63, q = lane >> 4, l16 = lane & 15;
    const int wm = wid >> 1, wn = wid & 1;

    __shared__ uint4 sA[512];        // 128 rows x 32 bf16 (64B/row)
    __shared__ uint4 sB[512];        // 128 cols x 32 bf16
    __shared__ float rs[2][128];

    f32x4 acc[4][4];
    f32x4 zf = {0.f, 0.f, 0.f, 0.f};
#pragma unroll
    for (int i = 0; i < 4; i++)
#pragma unroll
        for (int j = 0; j < 4; j++) acc[i][j] = zf;

    // staging maps: 2 threads per row/col, 16 k-values each
    const int arow = t >> 1, ahalf = t & 1;
    const __hip_bfloat16* aptr = A + (size_t)(row0 + arow) * lda + ahalf * 16;
    const int bcolg = col0 + (t >> 1);
    const int bkoff = (t & 1) * 16;
    const float* brow = nullptr;
    if (bcolg < Nsplit)      brow = B  + (size_t)bcolg * K;
    else if (bcolg < Nmat)   brow = B2 + (size_t)(bcolg - Nsplit) * K;

    uint4* adst = &sA[(t >> 1) * 4 + (t & 1) * 2];
    uint4* bdst = &sB[(t >> 1) * 4 + (t & 1) * 2];
    const bf16x8* sAv = (const bf16x8*)sA;
    const bf16x8* sBv = (const bf16x8*)sB;

    for (int k0 = 0; k0 < Kloop; k0 += 32) {
        uint4 av0 = ((const uint4*)(aptr + k0))[0];
        uint4 av1 = ((const uint4*)(aptr + k0))[1];
        float4 f0, f1, f2, f3;
        if (brow != nullptr && (k0 + bkoff) < K) {
            const float4* bp = (const float4*)(brow + k0 + bkoff);
            f0 = bp[0]; f1 = bp[1]; f2 = bp[2]; f3 = bp[3];
        } else {
            f0 = make_float4(0.f, 0.f, 0.f, 0.f);
            f1 = f0; f2 = f0; f3 = f0;
        }
        __hip_bfloat16 hb[16] __attribute__((aligned(16)));
        hb[0]  = __float2bfloat16(f0.x); hb[1]  = __float2bfloat16(f0.y);
        hb[2]  = __float2bfloat16(f0.z); hb[3]  = __float2bfloat16(f0.w);
        hb[4]  = __float2bfloat16(f1.x); hb[5]  = __float2bfloat16(f1.y);
        hb[6]  = __float2bfloat16(f1.z); hb[7]  = __float2bfloat16(f1.w);
        hb[8]  = __float2bfloat16(f2.x); hb[9]  = __float2bfloat16(f2.y);
        hb[10] = __float2bfloat16(f2.z); hb[11] = __float2bfloat16(f2.w);
        hb[12] = __float2bfloat16(f3.x); hb[13] = __float2bfloat16(f3.y);
        hb[14] = __float2bfloat16(f3.z); hb[15] = __float2bfloat16(f3.w);

        __syncthreads();
        adst[0] = av0; adst[1] = av1;
        bdst[0] = ((uint4*)hb)[0]; bdst[1] = ((uint4*)hb)[1];
        __syncthreads();

        bf16x8 af[4], bfr[4];
#pragma unroll
        for (int i = 0; i < 4; i++) af[i]  = sAv[(wm * 64 + i * 16 + l16) * 4 + q];
#pragma unroll
        for (int j = 0; j < 4; j++) bfr[j] = sBv[(wn * 64 + j * 16 + l16) * 4 + q];
#pragma unroll
        for (int i = 0; i < 4; i++)
#pragma unroll
            for (int j = 0; j < 4; j++)
                acc[i][j] = __builtin_amdgcn_mfma_f32_16x16x32_bf16(af[i], bfr[j], acc[i][j], 0, 0, 0);
    }

    int colg[4];
#pragma unroll
    for (int j = 0; j < 4; j++) colg[j] = col0 + wn * 64 + j * 16 + l16;

    if (MODE == MODE_Y) {
#pragma unroll
        for (int i = 0; i < 4; i++) {
            int rbase = row0 + wm * 64 + i * 16 + q * 4;
#pragma unroll
            for (int j = 0; j < 4; j++) {
                if (colg[j] < ywidth) {
#pragma unroll
                    for (int r = 0; r < 4; r++)
                        yout[(size_t)(rbase + r) * yld + colg[j]] = __float2bfloat16(acc[i][j][r]);
                }
            }
        }
    } else if (MODE == MODE_REDUCE) {
        float bv[4]; bool ok[4];
#pragma unroll
        for (int j = 0; j < 4; j++) {
            ok[j] = colg[j] < Nmat;
            bv[j] = colg[j] < Nsplit ? bias[colg[j]] : (ok[j] ? bias2[colg[j] - Nsplit] : 0.f);
        }
#pragma unroll
        for (int i = 0; i < 4; i++) {
#pragma unroll
            for (int r = 0; r < 4; r++) {
                float s = 0.f;
#pragma unroll
                for (int j = 0; j < 4; j++)
                    if (ok[j]) s += __expf(acc[i][j][r] + bv[j]);
                s += __shfl_xor(s, 1);
                s += __shfl_xor(s, 2);
                s += __shfl_xor(s, 4);
                s += __shfl_xor(s, 8);
                if (l16 == 0) rs[wn][wm * 64 + i * 16 + q * 4 + r] = s;
            }
        }
        __syncthreads();
        if (t < 128) atomicAdd(&rowsum[row0 + t], rs[0][t] + rs[1][t]);
    } else { // MODE_WRITE
        float bv[4];
#pragma unroll
        for (int j = 0; j < 4; j++)
            bv[j] = colg[j] < Nsplit ? bias[colg[j]] : (colg[j] < Nmat ? bias2[colg[j] - Nsplit] : 0.f);
#pragma unroll
        for (int i = 0; i < 4; i++) {
            int rbase = row0 + wm * 64 + i * 16 + q * 4;
#pragma unroll
            for (int r = 0; r < 4; r++) {
                int rg = rbase + r;
                float av = adj[rg];
                float* orow = outp + (size_t)rg * VOCAB_SZ;
#pragma unroll
                for (int j = 0; j < 4; j++)
                    if (colg[j] < Nstore)
                        __builtin_nontemporal_store(acc[i][j][r] + bv[j] + av, orow + colg[j]);
            }
        }
    }
}

__global__ void prep_k(const float* __restrict__ h, __hip_bfloat16* __restrict__ hb,
                       float* __restrict__ rowsum)
{
    int gid = blockIdx.x * 256 + threadIdx.x;
    if (gid < NROWS * 1024) hb[gid] = __float2bfloat16(h[gid]);
    if (gid < 2048) rowsum[gid] = 0.f;
}

__global__ void finalize_k(const float* __restrict__ rowsum, const __hip_bfloat16* __restrict__ y0,
                           const float* __restrict__ cw, const float* __restrict__ cb,
                           float* __restrict__ adj)
{
    int r = threadIdx.x; // 512 threads, 1 block
    float lse0 = logf(rowsum[r]);
    float h0 = cb[0], h1 = cb[1], h2 = cb[2];
    for (int d = 0; d < 1024; d++) {
        float yv = __bfloat162float(y0[r * 1024 + d]);
        h0 += yv * cw[d];
        h1 += yv * cw[1024 + d];
        h2 += yv * cw[2048 + d];
    }
    adj[r]        = -lse0;
    adj[512 + r]  = h0 - lse0 - logf(rowsum[512 + r]);
    adj[1024 + r] = h1 - lse0 - logf(rowsum[1024 + r]);
    adj[1536 + r] = h2 - lse0 - logf(rowsum[1536 + r]);
}

__global__ void loss_k(const float* __restrict__ out, const int* __restrict__ tgt,
                       float* __restrict__ lossp)
{
    __shared__ float sm[512];
    int t = threadIdx.x;
    sm[t] = out[(size_t)t * VOCAB_SZ + tgt[t]];
    __syncthreads();
    for (int s = 256; s > 0; s >>= 1) {
        if (t < s) sm[t] += sm[t + s];
        __syncthreads();
    }
    if (t == 0) lossp[0] = -sm[0] / 512.f;
}

extern "C" void kernel_launch(void* const* d_in, const int* in_sizes, int n_in,
                              void* d_out, int out_size, void* d_ws, size_t ws_size,
                              hipStream_t stream)
{
    const float* hidden = (const float*)d_in[0];
    const int*   target = (const int*)d_in[1];
    const float* cw     = (const float*)d_in[2];
    const float* cb     = (const float*)d_in[3];
    const float* proj[4] = {(const float*)d_in[4], (const float*)d_in[7],
                            (const float*)d_in[10], (const float*)d_in[13]};
    const float* W[4]    = {(const float*)d_in[5], (const float*)d_in[8],
                            (const float*)d_in[11], (const float*)d_in[14]};
    const float* bb[4]   = {(const float*)d_in[6], (const float*)d_in[9],
                            (const float*)d_in[12], (const float*)d_in[15]};
    float* out = (float*)d_out;

    char* ws = (char*)d_ws;
    __hip_bfloat16* hb = (__hip_bfloat16*)ws;                     // 512x1024 bf16
    __hip_bfloat16* y0 = (__hip_bfloat16*)(ws + 1048576);         // 512x1024
    __hip_bfloat16* y1 = (__hip_bfloat16*)(ws + 2097152);         // 512x256
    __hip_bfloat16* y2 = (__hip_bfloat16*)(ws + 2359296);         // 512x64
    __hip_bfloat16* y3 = (__hip_bfloat16*)(ws + 2424832);         // 512x32 (K=16 zero-padded)
    float* rowsum = (float*)(ws + 2490368);                       // [4][512]
    float* adj    = (float*)(ws + 2498560);                       // [4][512]

    prep_k<<<2048, 256, 0, stream>>>(hidden, hb, rowsum);

    // y_i = hidden @ proj_i^T  (bf16 out)
    gemm_k<MODE_Y><<<dim3(8, 4), 256, 0, stream>>>(hb, 1024, 1024, 1024, proj[0], proj[0],
        1024, 1024, nullptr, nullptr, nullptr, nullptr, nullptr, 0, y0, 1024, 1024);
    gemm_k<MODE_Y><<<dim3(2, 4), 256, 0, stream>>>(hb, 1024, 1024, 1024, proj[1], proj[1],
        256, 256, nullptr, nullptr, nullptr, nullptr, nullptr, 0, y1, 256, 256);
    gemm_k<MODE_Y><<<dim3(1, 4), 256, 0, stream>>>(hb, 1024, 1024, 1024, proj[2], proj[2],
        64, 64, nullptr, nullptr, nullptr, nullptr, nullptr, 0, y2, 64, 64);
    gemm_k<MODE_Y><<<dim3(1, 4), 256, 0, stream>>>(hb, 1024, 1024, 1024, proj[3], proj[3],
        16, 16, nullptr, nullptr, nullptr, nullptr, nullptr, 0, y3, 32, 32);

    // pass 1: rowsum[i][r] = sum_n exp(logit + bias)
    gemm_k<MODE_REDUCE><<<dim3(157, 4), 256, 0, stream>>>(y0, 1024, 1024, 1024, W[0], cw,
        20003, 20000, bb[0], cb, rowsum, nullptr, nullptr, 0, nullptr, 0, 0);
    gemm_k<MODE_REDUCE><<<dim3(157, 4), 256, 0, stream>>>(y1, 256, 256, 256, W[1], W[1],
        20000, 20000, bb[1], bb[1], rowsum + 512, nullptr, nullptr, 0, nullptr, 0, 0);
    gemm_k<MODE_REDUCE><<<dim3(1250, 4), 256, 0, stream>>>(y2, 64, 64, 64, W[2], W[2],
        160000, 160000, bb[2], bb[2], rowsum + 1024, nullptr, nullptr, 0, nullptr, 0, 0);
    gemm_k<MODE_REDUCE><<<dim3(530, 4), 256, 0, stream>>>(y3, 32, 32, 16, W[3], W[3],
        67735, 67735, bb[3], bb[3], rowsum + 1536, nullptr, nullptr, 0, nullptr, 0, 0);

    finalize_k<<<1, 512, 0, stream>>>(rowsum, y0, cw, cb, adj);

    // pass 2: out = logit + bias + adj   (adj = head_cluster_logprob - lse terms)
    gemm_k<MODE_WRITE><<<dim3(157, 4), 256, 0, stream>>>(y0, 1024, 1024, 1024, W[0], cw,
        20003, 20000, bb[0], cb, nullptr, adj, out, 20000, nullptr, 0, 0);
    gemm_k<MODE_WRITE><<<dim3(157, 4), 256, 0, stream>>>(y1, 256, 256, 256, W[1], W[1],
        20000, 20000, bb[1], bb[1], nullptr, adj + 512, out + 20000, 20000, nullptr, 0, 0);
    gemm_k<MODE_WRITE><<<dim3(1250, 4), 256, 0, stream>>>(y2, 64, 64, 64, W[2], W[2],
        160000, 160000, bb[2], bb[2], nullptr, adj + 1024, out + 40000, 160000, nullptr, 0, 0);
    gemm_k<MODE_WRITE><<<dim3(530, 4), 256, 0, stream>>>(y3, 32, 32, 16, W[3], W[3],
        67735, 67735, bb[3], bb[3], nullptr, adj + 1536, out + 200000, 67735, nullptr, 0, 0);

    loss_k<<<1, 512, 0, stream>>>(out, target, out + (out_size - 1));
}